// Round 5
// baseline (1022.821 us; speedup 1.0000x reference)
//
#include <hip/hip_runtime.h>
#include <hip/hip_cooperative_groups.h>
#include <math.h>

namespace cg = cooperative_groups;

#define N_NODES 8192
#define CAP 128           // max neighbors/row; Binom(8192,0.004) mean~33 max~56, +self-loop
#define LRELU_ALPHA 0.2f

typedef float v4f __attribute__((ext_vector_type(4)));

// ---------- dense fc + attention projections (8 rows/tile, 256 thr) ----------
template <int K>
__device__ __forceinline__ void gemm_srcdst_body(
    int r0, int t, const float* __restrict__ A, const float* __restrict__ W,
    const float* __restrict__ a, float* __restrict__ Wh, float* __restrict__ src,
    float* __restrict__ dst, float* As, float (*red)[4][2]) {
  int c = t & 127, half = t >> 7;
  const float4* Ab4 = (const float4*)(A + (size_t)r0 * K);
  float4* As4 = (float4*)As;
#pragma unroll
  for (int l = t; l < 8 * K / 4; l += 256) As4[l] = Ab4[l];
  __syncthreads();
  float acc[4] = {0.f, 0.f, 0.f, 0.f};
  const float* Asl = As + (half * 4) * K;
#pragma unroll 8
  for (int k = 0; k < K; k++) {
    float wv = W[k * 128 + c];
#pragma unroll
    for (int r = 0; r < 4; r++) acc[r] += Asl[r * K + k] * wv;
  }
  float as = a[c], ad = a[128 + c];
  int wv_id = t >> 6, lane = t & 63;
#pragma unroll
  for (int r = 0; r < 4; r++) {
    int row = half * 4 + r;
    Wh[(size_t)(r0 + row) * 128 + c] = acc[r];
    float s = acc[r] * as, d = acc[r] * ad;
#pragma unroll
    for (int off = 32; off; off >>= 1) {
      s += __shfl_xor(s, off);
      d += __shfl_xor(d, off);
    }
    if (lane == 0) { red[wv_id][r][0] = s; red[wv_id][r][1] = d; }
  }
  __syncthreads();
  if (t < 8) {
    int wa = (t < 4) ? 0 : 2, rr = t & 3;
    src[r0 + t] = red[wa][rr][0] + red[wa + 1][rr][0];
    dst[r0 + t] = red[wa][rr][1] + red[wa + 1][rr][1];
  }
  __syncthreads();
}

// ---------- one adj row -> compacted neighbor list in global ----------
__device__ __forceinline__ void scan_row(int i, int t, const float* __restrict__ adj,
                                         int* __restrict__ idxbuf, int* __restrict__ counts,
                                         int* jn, int* cntp) {
  if (t == 0) *cntp = 0;
  __syncthreads();
  const v4f* row = (const v4f*)(adj + (size_t)i * N_NODES);
  v4f v[8];
#pragma unroll
  for (int u = 0; u < 8; u++) v[u] = __builtin_nontemporal_load(row + t + 256 * u);
#pragma unroll
  for (int u = 0; u < 8; u++) {
    int n = (v[u].x > 0.f) + (v[u].y > 0.f) + (v[u].z > 0.f) + (v[u].w > 0.f);
    if (n) {  // ~1.6% of threads
      int p = atomicAdd(cntp, n);
      int j0 = (t + 256 * u) * 4;
      if (v[u].x > 0.f) { if (p < CAP) jn[p] = j0;     p++; }
      if (v[u].y > 0.f) { if (p < CAP) jn[p] = j0 + 1; p++; }
      if (v[u].z > 0.f) { if (p < CAP) jn[p] = j0 + 2; p++; }
      if (v[u].w > 0.f) { if (p < CAP) jn[p] = j0 + 3; p++; }
    }
  }
  __syncthreads();
  int c = *cntp;
  if (c > CAP) c = CAP;
  if (t < c) idxbuf[(size_t)i * CAP + t] = jn[t];
  if (t == 0) counts[i] = c;
  __syncthreads();
}

// ---------- GAT aggregate for one node (256 thr, split-k gather) ----------
__device__ __forceinline__ void agg_body(int i, int t, const float* __restrict__ Wh,
                                         const float* __restrict__ src,
                                         const float* __restrict__ dst,
                                         const int* __restrict__ idxbuf,
                                         const int* __restrict__ counts,
                                         float* __restrict__ outp, int* jn, float* w,
                                         float* redm, float* reds, float* accs) {
  int lane = t & 63, wv = t >> 6;
  int c = counts[i];
  float si = src[i];
  float e = -1e30f;
  if (t < c) {
    int j = idxbuf[(size_t)i * CAP + t];
    jn[t] = j;
    float x = si + dst[j];
    e = x > 0.f ? x : LRELU_ALPHA * x;
  }
  float m = e;
#pragma unroll
  for (int off = 32; off; off >>= 1) m = fmaxf(m, __shfl_xor(m, off));
  if (lane == 0) redm[wv] = m;
  __syncthreads();
  float M = fmaxf(fmaxf(redm[0], redm[1]), fmaxf(redm[2], redm[3]));
  float ex = 0.f;
  if (t < c) {
    ex = expf(e - M);
    w[t] = ex;
  }
  float s = ex;
#pragma unroll
  for (int off = 32; off; off >>= 1) s += __shfl_xor(s, off);
  if (lane == 0) reds[wv] = s;
  __syncthreads();  // publishes w[]/jn[]
  float inv = 1.f / (reds[0] + reds[1] + reds[2] + reds[3]);
  int col = t & 127, half = t >> 7;
  float acc = 0.f;
  int k = half;
  for (; k + 2 < c; k += 4)
    acc += w[k] * Wh[(size_t)jn[k] * 128 + col] + w[k + 2] * Wh[(size_t)jn[k + 2] * 128 + col];
  for (; k < c; k += 2) acc += w[k] * Wh[(size_t)jn[k] * 128 + col];
  if (half == 0) accs[col] = acc;
  __syncthreads();
  if (half == 1) {
    float a = (accs[col] + acc) * inv;
    outp[(size_t)i * 128 + col] = a > 0.f ? a : expf(a) - 1.f;  // ELU
  }
  __syncthreads();
}

// ---------- GRU for one 8-row tile ----------
__device__ __forceinline__ void gru_body(int r0, int t, const float* __restrict__ x,
                                         const float* __restrict__ h,
                                         const float* __restrict__ WiT,
                                         const float* __restrict__ WhT,
                                         const float* __restrict__ b_ih,
                                         const float* __restrict__ b_hh,
                                         float* __restrict__ outp, float* xs, float* hs) {
  int c = t & 127, half = t >> 7;
  ((float4*)xs)[t] = ((const float4*)(x + (size_t)r0 * 128))[t];
  ((float4*)hs)[t] = ((const float4*)(h + (size_t)r0 * 128))[t];
  __syncthreads();
  const float* xsl = xs + half * 4 * 128;
  const float* hsl = hs + half * 4 * 128;
  float rg[4], zg[4];
  {
    float ai[4] = {0.f}, ah[4] = {0.f};
#pragma unroll 4
    for (int k = 0; k < 128; k++) {
      float wi = WiT[k * 384 + c], wh = WhT[k * 384 + c];
#pragma unroll
      for (int r = 0; r < 4; r++) { ai[r] += xsl[r * 128 + k] * wi; ah[r] += hsl[r * 128 + k] * wh; }
    }
    float bi = b_ih[c], bh = b_hh[c];
#pragma unroll
    for (int r = 0; r < 4; r++) rg[r] = 1.f / (1.f + expf(-(ai[r] + bi + ah[r] + bh)));
  }
  {
    float ai[4] = {0.f}, ah[4] = {0.f};
#pragma unroll 4
    for (int k = 0; k < 128; k++) {
      float wi = WiT[k * 384 + 128 + c], wh = WhT[k * 384 + 128 + c];
#pragma unroll
      for (int r = 0; r < 4; r++) { ai[r] += xsl[r * 128 + k] * wi; ah[r] += hsl[r * 128 + k] * wh; }
    }
    float bi = b_ih[128 + c], bh = b_hh[128 + c];
#pragma unroll
    for (int r = 0; r < 4; r++) zg[r] = 1.f / (1.f + expf(-(ai[r] + bi + ah[r] + bh)));
  }
  {
    float ai[4] = {0.f}, ah[4] = {0.f};
#pragma unroll 4
    for (int k = 0; k < 128; k++) {
      float wi = WiT[k * 384 + 256 + c], wh = WhT[k * 384 + 256 + c];
#pragma unroll
      for (int r = 0; r < 4; r++) { ai[r] += xsl[r * 128 + k] * wi; ah[r] += hsl[r * 128 + k] * wh; }
    }
    float bi = b_ih[256 + c], bh = b_hh[256 + c];
#pragma unroll
    for (int r = 0; r < 4; r++) {
      float n = tanhf(ai[r] + bi + rg[r] * (ah[r] + bh));
      outp[(size_t)(r0 + half * 4 + r) * 128 + c] =
          (1.f - zg[r]) * n + zg[r] * hsl[r * 128 + c];
    }
  }
  __syncthreads();
}

// ================= the whole pipeline as ONE cooperative dispatch =================
__global__ __launch_bounds__(256, 4) void mega_kernel(
    const float* __restrict__ x, const float* __restrict__ adj, const float* __restrict__ hprev,
    const float* __restrict__ W1, const float* __restrict__ a1, const float* __restrict__ W2,
    const float* __restrict__ a2, const float* __restrict__ Wi, const float* __restrict__ Whm,
    const float* __restrict__ b_ih, const float* __restrict__ b_hh, float* __restrict__ outp,
    float* __restrict__ Wh1, float* __restrict__ Wh2, float* __restrict__ x1,
    float* __restrict__ h_spat, float* __restrict__ src1, float* __restrict__ dst1,
    float* __restrict__ src2, float* __restrict__ dst2, float* __restrict__ WiT,
    float* __restrict__ WhT, int* __restrict__ counts, int* __restrict__ idxbuf, int NB) {
  cg::grid_group grid = cg::this_grid();
  __shared__ float As[8 * 256];
  __shared__ float red[4][4][2];
  __shared__ int jn[CAP];
  __shared__ float w[CAP];
  __shared__ float redm[4];
  __shared__ float reds[4];
  __shared__ float accs[128];
  __shared__ int cnt;
  int b = blockIdx.x, t = threadIdx.x;

  // ---- Phase A: gemm1+srcdst1 || GRU-weight transpose || adj scan (independent) ----
  // even blocks compute-first, odd blocks scan-first so the HBM stream starts at t=0
  if (b & 1) {
    for (int i = b; i < N_NODES; i += NB) scan_row(i, t, adj, idxbuf, counts, jn, &cnt);
    for (int n = b * 256 + t; n < 384 * 128; n += NB * 256) {
      int r = n >> 7, c = n & 127;
      WiT[c * 384 + r] = Wi[n];
      WhT[c * 384 + r] = Whm[n];
    }
    for (int tile = b; tile < 1024; tile += NB)
      gemm_srcdst_body<256>(tile * 8, t, x, W1, a1, Wh1, src1, dst1, As, red);
  } else {
    for (int n = b * 256 + t; n < 384 * 128; n += NB * 256) {
      int r = n >> 7, c = n & 127;
      WiT[c * 384 + r] = Wi[n];
      WhT[c * 384 + r] = Whm[n];
    }
    for (int tile = b; tile < 1024; tile += NB)
      gemm_srcdst_body<256>(tile * 8, t, x, W1, a1, Wh1, src1, dst1, As, red);
    for (int i = b; i < N_NODES; i += NB) scan_row(i, t, adj, idxbuf, counts, jn, &cnt);
  }
  __threadfence();
  grid.sync();

  // ---- Phase B: GAT layer-1 aggregate ----
  for (int i = b; i < N_NODES; i += NB)
    agg_body(i, t, Wh1, src1, dst1, idxbuf, counts, x1, jn, w, redm, reds, accs);
  __threadfence();
  grid.sync();

  // ---- Phase C: layer-2 fc + projections ----
  for (int tile = b; tile < 1024; tile += NB)
    gemm_srcdst_body<128>(tile * 8, t, x1, W2, a2, Wh2, src2, dst2, As, red);
  __threadfence();
  grid.sync();

  // ---- Phase D: GAT layer-2 aggregate ----
  for (int i = b; i < N_NODES; i += NB)
    agg_body(i, t, Wh2, src2, dst2, idxbuf, counts, h_spat, jn, w, redm, reds, accs);
  __threadfence();
  grid.sync();

  // ---- Phase E: GRU ----
  for (int tile = b; tile < 1024; tile += NB)
    gru_body(tile * 8, t, h_spat, hprev, WiT, WhT, b_ih, b_hh, outp, As, As + 1024);
}

extern "C" void kernel_launch(void* const* d_in, const int* in_sizes, int n_in,
                              void* d_out, int out_size, void* d_ws, size_t ws_size,
                              hipStream_t stream) {
  const float* x     = (const float*)d_in[0];
  const float* adj   = (const float*)d_in[1];
  const float* hprev = (const float*)d_in[2];
  const float* W1    = (const float*)d_in[3];
  const float* a1    = (const float*)d_in[4];
  const float* W2    = (const float*)d_in[5];
  const float* a2    = (const float*)d_in[6];
  const float* Wi    = (const float*)d_in[7];
  const float* Whm   = (const float*)d_in[8];
  const float* b_ih  = (const float*)d_in[9];
  const float* b_hh  = (const float*)d_in[10];
  float* outp = (float*)d_out;

  char* p = (char*)d_ws;
  float* Wh1    = (float*)p; p += (size_t)N_NODES * 128 * 4;
  float* Wh2    = (float*)p; p += (size_t)N_NODES * 128 * 4;
  float* x1     = (float*)p; p += (size_t)N_NODES * 128 * 4;
  float* h_spat = (float*)p; p += (size_t)N_NODES * 128 * 4;
  float* src1   = (float*)p; p += (size_t)N_NODES * 4;
  float* dst1   = (float*)p; p += (size_t)N_NODES * 4;
  float* src2   = (float*)p; p += (size_t)N_NODES * 4;
  float* dst2   = (float*)p; p += (size_t)N_NODES * 4;
  float* WiT    = (float*)p; p += (size_t)384 * 128 * 4;
  float* WhT    = (float*)p; p += (size_t)384 * 128 * 4;
  int*   counts = (int*)p;   p += (size_t)N_NODES * 4;
  int*   idxbuf = (int*)p;   p += (size_t)N_NODES * CAP * 4;

  // co-residency-validated grid size (deterministic across calls)
  int maxb = 0;
  if (hipOccupancyMaxActiveBlocksPerMultiprocessor(
          &maxb, reinterpret_cast<const void*>(mega_kernel), 256, 0) != hipSuccess ||
      maxb < 1)
    maxb = 2;
  int nb = maxb * 256;
  if (nb > 1024) nb = 1024;

  void* args[] = {(void*)&x,     (void*)&adj,   (void*)&hprev, (void*)&W1,   (void*)&a1,
                  (void*)&W2,    (void*)&a2,    (void*)&Wi,    (void*)&Whm,  (void*)&b_ih,
                  (void*)&b_hh,  (void*)&outp,  (void*)&Wh1,   (void*)&Wh2,  (void*)&x1,
                  (void*)&h_spat,(void*)&src1,  (void*)&dst1,  (void*)&src2, (void*)&dst2,
                  (void*)&WiT,   (void*)&WhT,   (void*)&counts,(void*)&idxbuf,(void*)&nb};
  hipLaunchCooperativeKernel((const void*)mega_kernel, dim3(nb), dim3(256), args, 0, stream);
}

// Round 6
// 473.895 us; speedup vs baseline: 2.1583x; 2.1583x over previous
//
#include <hip/hip_runtime.h>
#include <math.h>

#define N_NODES 8192
#define CAP 128           // max neighbors/row; Binom(8192,0.004) mean~33 max~56, +self-loop
#define LRELU_ALPHA 0.2f

typedef float v4f __attribute__((ext_vector_type(4)));

// ---------- gemm core on a pre-staged LDS A-tile (8 rows x K), 256 thr ----------
// Wh[r,c] = sum_k A[r,k] W[k,c];  src = Wh·a[0:128];  dst = Wh·a[128:256]
template <int K>
__device__ __forceinline__ void gemm_from_lds(
    int r0, int t, const float* As, const float* __restrict__ W,
    const float* __restrict__ a, float* __restrict__ Wh, float* __restrict__ src,
    float* __restrict__ dst, float (*red)[4][2]) {
  int c = t & 127, half = t >> 7;
  float acc[4] = {0.f, 0.f, 0.f, 0.f};
  const float* Asl = As + (half * 4) * K;
#pragma unroll 8
  for (int k = 0; k < K; k++) {
    float wv = W[k * 128 + c];
#pragma unroll
    for (int r = 0; r < 4; r++) acc[r] += Asl[r * K + k] * wv;
  }
  float as = a[c], ad = a[128 + c];
  int wv_id = t >> 6, lane = t & 63;
#pragma unroll
  for (int r = 0; r < 4; r++) {
    int row = half * 4 + r;
    Wh[(size_t)(r0 + row) * 128 + c] = acc[r];
    float s = acc[r] * as, d = acc[r] * ad;
#pragma unroll
    for (int off = 32; off; off >>= 1) {
      s += __shfl_xor(s, off);
      d += __shfl_xor(d, off);
    }
    if (lane == 0) { red[wv_id][r][0] = s; red[wv_id][r][1] = d; }
  }
  __syncthreads();
  if (t < 8) {
    int wa = (t < 4) ? 0 : 2, rr = t & 3;
    src[r0 + t] = red[wa][rr][0] + red[wa + 1][rr][0];
    dst[r0 + t] = red[wa][rr][1] + red[wa + 1][rr][1];
  }
}

// ---------- GAT aggregate for one node -> LDS tile row (256 thr, 4-deep gather) ----------
__device__ __forceinline__ void agg_to_lds(
    int i, int q, int t, const float* __restrict__ Wh, const float* __restrict__ src,
    const float* __restrict__ dst, const int* __restrict__ idxbuf,
    const int* __restrict__ counts, float* tile, int* jn, float* w, float* redm, float* reds,
    float* accs) {
  int lane = t & 63, wv = t >> 6;
  int c = counts[i];
  float si = src[i];
  float e = -1e30f;
  if (t < c) {
    int j = idxbuf[(size_t)i * CAP + t];
    jn[t] = j;
    float x = si + dst[j];
    e = x > 0.f ? x : LRELU_ALPHA * x;
  }
  float m = e;
#pragma unroll
  for (int off = 32; off; off >>= 1) m = fmaxf(m, __shfl_xor(m, off));
  if (lane == 0) redm[wv] = m;
  __syncthreads();
  float M = fmaxf(fmaxf(redm[0], redm[1]), fmaxf(redm[2], redm[3]));
  float ex = 0.f;
  if (t < c) {
    ex = expf(e - M);
    w[t] = ex;
  }
  float s = ex;
#pragma unroll
  for (int off = 32; off; off >>= 1) s += __shfl_xor(s, off);
  if (lane == 0) reds[wv] = s;
  __syncthreads();  // publishes w[]/jn[]
  float inv = 1.f / (reds[0] + reds[1] + reds[2] + reds[3]);
  int col = t & 127, half = t >> 7;
  float acc = 0.f;
  int k = half;
  for (; k + 6 < c; k += 8)  // 4 independent loads in flight per iteration
    acc += w[k] * Wh[(size_t)jn[k] * 128 + col] + w[k + 2] * Wh[(size_t)jn[k + 2] * 128 + col] +
           w[k + 4] * Wh[(size_t)jn[k + 4] * 128 + col] +
           w[k + 6] * Wh[(size_t)jn[k + 6] * 128 + col];
  for (; k < c; k += 2) acc += w[k] * Wh[(size_t)jn[k] * 128 + col];
  if (half == 0) accs[col] = acc;
  __syncthreads();
  if (half == 1) {
    float a = (accs[col] + acc) * inv;
    tile[q * 128 + col] = a > 0.f ? a : expf(a) - 1.f;  // ELU, stays in LDS
  }
  __syncthreads();
}

// ======= kernel A: adj scan (blocks 0..8191) || gemm1+srcdst1 (..9215) || transpose (..9279) ==
__global__ __launch_bounds__(256) void kA(
    const float* __restrict__ adj, int* __restrict__ idxbuf, int* __restrict__ counts,
    const float* __restrict__ x, const float* __restrict__ W1, const float* __restrict__ a1,
    float* __restrict__ Wh1, float* __restrict__ src1, float* __restrict__ dst1,
    const float* __restrict__ Wi, const float* __restrict__ Whm, float* __restrict__ WiT,
    float* __restrict__ WhT) {
  __shared__ float As[8 * 256];
  __shared__ float red[4][4][2];
  __shared__ int jn[CAP];
  __shared__ int cnt;
  int t = threadIdx.x, b = blockIdx.x;
  if (b < N_NODES) {
    // ---- scan one adj row: 32 KB nontemporal stream, compact into LDS, write list ----
    if (t == 0) cnt = 0;
    __syncthreads();
    const v4f* row = (const v4f*)(adj + (size_t)b * N_NODES);
    v4f v[8];
#pragma unroll
    for (int u = 0; u < 8; u++) v[u] = __builtin_nontemporal_load(row + t + 256 * u);
#pragma unroll
    for (int u = 0; u < 8; u++) {
      int n = (v[u].x > 0.f) + (v[u].y > 0.f) + (v[u].z > 0.f) + (v[u].w > 0.f);
      if (n) {  // ~1.6% of threads
        int p = atomicAdd(&cnt, n);
        int j0 = (t + 256 * u) * 4;
        if (v[u].x > 0.f) { if (p < CAP) jn[p] = j0;     p++; }
        if (v[u].y > 0.f) { if (p < CAP) jn[p] = j0 + 1; p++; }
        if (v[u].z > 0.f) { if (p < CAP) jn[p] = j0 + 2; p++; }
        if (v[u].w > 0.f) { if (p < CAP) jn[p] = j0 + 3; p++; }
      }
    }
    __syncthreads();
    int c = cnt > CAP ? CAP : cnt;
    if (t < c) idxbuf[(size_t)b * CAP + t] = jn[t];
    if (t == 0) counts[b] = c;
  } else if (b < N_NODES + 1024) {
    int tile = b - N_NODES;
    const float4* Ab4 = (const float4*)(x + (size_t)tile * 8 * 256);
    float4* As4 = (float4*)As;
#pragma unroll
    for (int l = t; l < 8 * 256 / 4; l += 256) As4[l] = Ab4[l];
    __syncthreads();
    gemm_from_lds<256>(tile * 8, t, As, W1, a1, Wh1, src1, dst1, red);
  } else {
    for (int n = (b - N_NODES - 1024) * 256 + t; n < 384 * 128; n += 64 * 256) {
      int r = n >> 7, c = n & 127;
      WiT[c * 384 + r] = Wi[n];
      WhT[c * 384 + r] = Whm[n];
    }
  }
}

// ======= kernel B: agg1 for 8 nodes -> LDS tile -> gemm2+srcdst2 (x1 never hits global) ======
__global__ __launch_bounds__(256) void kB(
    const float* __restrict__ Wh1, const float* __restrict__ src1,
    const float* __restrict__ dst1, const int* __restrict__ idxbuf,
    const int* __restrict__ counts, const float* __restrict__ W2, const float* __restrict__ a2,
    float* __restrict__ Wh2, float* __restrict__ src2, float* __restrict__ dst2) {
  __shared__ float tile[8 * 128];
  __shared__ float red[4][4][2];
  __shared__ int jn[CAP];
  __shared__ float w[CAP];
  __shared__ float redm[4];
  __shared__ float reds[4];
  __shared__ float accs[128];
  int t = threadIdx.x, b = blockIdx.x;
  int i0 = b * 8;
#pragma unroll 1
  for (int q = 0; q < 8; q++)
    agg_to_lds(i0 + q, q, t, Wh1, src1, dst1, idxbuf, counts, tile, jn, w, redm, reds, accs);
  // tile = x1 rows i0..i0+7 (ELU applied); barriers inside agg_to_lds ordered everything
  gemm_from_lds<128>(i0, t, tile, W2, a2, Wh2, src2, dst2, red);
}

// ======= kernel C: agg2 for 8 nodes -> LDS tile -> GRU (h_spat never hits global) ======
__global__ __launch_bounds__(256) void kC(
    const float* __restrict__ Wh2, const float* __restrict__ src2,
    const float* __restrict__ dst2, const int* __restrict__ idxbuf,
    const int* __restrict__ counts, const float* __restrict__ hprev,
    const float* __restrict__ WiT, const float* __restrict__ WhT,
    const float* __restrict__ b_ih, const float* __restrict__ b_hh, float* __restrict__ outp) {
  __shared__ float tile[8 * 128];  // h_spat rows (GRU x-input)
  __shared__ float hs[8 * 128];    // hprev rows
  __shared__ int jn[CAP];
  __shared__ float w[CAP];
  __shared__ float redm[4];
  __shared__ float reds[4];
  __shared__ float accs[128];
  int t = threadIdx.x, b = blockIdx.x;
  int i0 = b * 8;
  // stage hprev early (independent of agg; ordered by the many barriers before use)
  ((float4*)hs)[t] = ((const float4*)(hprev + (size_t)i0 * 128))[t];
#pragma unroll 1
  for (int q = 0; q < 8; q++)
    agg_to_lds(i0 + q, q, t, Wh2, src2, dst2, idxbuf, counts, tile, jn, w, redm, reds, accs);
  // ---- GRU on the tile ----
  int c = t & 127, half = t >> 7;
  const float* xsl = tile + half * 4 * 128;
  const float* hsl = hs + half * 4 * 128;
  float rg[4], zg[4];
  {
    float ai[4] = {0.f}, ah[4] = {0.f};
#pragma unroll 4
    for (int k = 0; k < 128; k++) {
      float wi = WiT[k * 384 + c], wh = WhT[k * 384 + c];
#pragma unroll
      for (int r = 0; r < 4; r++) { ai[r] += xsl[r * 128 + k] * wi; ah[r] += hsl[r * 128 + k] * wh; }
    }
    float bi = b_ih[c], bh = b_hh[c];
#pragma unroll
    for (int r = 0; r < 4; r++) rg[r] = 1.f / (1.f + expf(-(ai[r] + bi + ah[r] + bh)));
  }
  {
    float ai[4] = {0.f}, ah[4] = {0.f};
#pragma unroll 4
    for (int k = 0; k < 128; k++) {
      float wi = WiT[k * 384 + 128 + c], wh = WhT[k * 384 + 128 + c];
#pragma unroll
      for (int r = 0; r < 4; r++) { ai[r] += xsl[r * 128 + k] * wi; ah[r] += hsl[r * 128 + k] * wh; }
    }
    float bi = b_ih[128 + c], bh = b_hh[128 + c];
#pragma unroll
    for (int r = 0; r < 4; r++) zg[r] = 1.f / (1.f + expf(-(ai[r] + bi + ah[r] + bh)));
  }
  {
    float ai[4] = {0.f}, ah[4] = {0.f};
#pragma unroll 4
    for (int k = 0; k < 128; k++) {
      float wi = WiT[k * 384 + 256 + c], wh = WhT[k * 384 + 256 + c];
#pragma unroll
      for (int r = 0; r < 4; r++) { ai[r] += xsl[r * 128 + k] * wi; ah[r] += hsl[r * 128 + k] * wh; }
    }
    float bi = b_ih[256 + c], bh = b_hh[256 + c];
#pragma unroll
    for (int r = 0; r < 4; r++) {
      float n = tanhf(ai[r] + bi + rg[r] * (ah[r] + bh));
      outp[(size_t)(i0 + half * 4 + r) * 128 + c] =
          (1.f - zg[r]) * n + zg[r] * hsl[r * 128 + c];
    }
  }
}

extern "C" void kernel_launch(void* const* d_in, const int* in_sizes, int n_in,
                              void* d_out, int out_size, void* d_ws, size_t ws_size,
                              hipStream_t stream) {
  const float* x     = (const float*)d_in[0];
  const float* adj   = (const float*)d_in[1];
  const float* hprev = (const float*)d_in[2];
  const float* W1    = (const float*)d_in[3];
  const float* a1    = (const float*)d_in[4];
  const float* W2    = (const float*)d_in[5];
  const float* a2    = (const float*)d_in[6];
  const float* Wi    = (const float*)d_in[7];
  const float* Whm   = (const float*)d_in[8];
  const float* b_ih  = (const float*)d_in[9];
  const float* b_hh  = (const float*)d_in[10];
  float* outp = (float*)d_out;

  char* p = (char*)d_ws;
  float* Wh1    = (float*)p; p += (size_t)N_NODES * 128 * 4;
  float* Wh2    = (float*)p; p += (size_t)N_NODES * 128 * 4;
  float* src1   = (float*)p; p += (size_t)N_NODES * 4;
  float* dst1   = (float*)p; p += (size_t)N_NODES * 4;
  float* src2   = (float*)p; p += (size_t)N_NODES * 4;
  float* dst2   = (float*)p; p += (size_t)N_NODES * 4;
  float* WiT    = (float*)p; p += (size_t)384 * 128 * 4;
  float* WhT    = (float*)p; p += (size_t)384 * 128 * 4;
  int*   counts = (int*)p;   p += (size_t)N_NODES * 4;
  int*   idxbuf = (int*)p;   p += (size_t)N_NODES * CAP * 4;

  // A: adj scan (8192 blocks, full parallelism) || gemm1+srcdst1 || GRU-weight transpose
  kA<<<N_NODES + 1024 + 64, 256, 0, stream>>>(adj, idxbuf, counts, x, W1, a1, Wh1, src1, dst1,
                                              Wi, Whm, WiT, WhT);
  // B: agg1 -> LDS x1 tile -> gemm2+srcdst2
  kB<<<N_NODES / 8, 256, 0, stream>>>(Wh1, src1, dst1, idxbuf, counts, W2, a2, Wh2, src2, dst2);
  // C: agg2 -> LDS h_spat tile -> GRU
  kC<<<N_NODES / 8, 256, 0, stream>>>(Wh2, src2, dst2, idxbuf, counts, hprev, WiT, WhT, b_ih,
                                      b_hh, outp);
}

// Round 7
// 452.389 us; speedup vs baseline: 2.2609x; 1.0475x over previous
//
#include <hip/hip_runtime.h>
#include <math.h>

#define N_NODES 8192
#define CAP 128           // max neighbors/row; Binom(8192,0.004) mean~33 max~56, +self-loop
#define LRELU_ALPHA 0.2f

typedef float v4f __attribute__((ext_vector_type(4)));

// ---------- gemm core on a pre-staged LDS A-tile (8 rows x K), 256 thr ----------
// Wh[r,c] = sum_k A[r,k] W[k,c];  src = Wh·a[0:128];  dst = Wh·a[128:256]
template <int K>
__device__ __forceinline__ void gemm_from_lds(
    int r0, int t, const float* As, const float* __restrict__ W,
    const float* __restrict__ a, float* __restrict__ Wh, float* __restrict__ src,
    float* __restrict__ dst, float (*red)[4][2]) {
  int c = t & 127, half = t >> 7;
  float acc[4] = {0.f, 0.f, 0.f, 0.f};
  const float* Asl = As + (half * 4) * K;
#pragma unroll 8
  for (int k = 0; k < K; k++) {
    float wv = W[k * 128 + c];
#pragma unroll
    for (int r = 0; r < 4; r++) acc[r] += Asl[r * K + k] * wv;
  }
  float as = a[c], ad = a[128 + c];
  int wv_id = t >> 6, lane = t & 63;
#pragma unroll
  for (int r = 0; r < 4; r++) {
    int row = half * 4 + r;
    Wh[(size_t)(r0 + row) * 128 + c] = acc[r];
    float s = acc[r] * as, d = acc[r] * ad;
#pragma unroll
    for (int off = 32; off; off >>= 1) {
      s += __shfl_xor(s, off);
      d += __shfl_xor(d, off);
    }
    if (lane == 0) { red[wv_id][r][0] = s; red[wv_id][r][1] = d; }
  }
  __syncthreads();
  if (t < 8) {
    int wa = (t < 4) ? 0 : 2, rr = t & 3;
    src[r0 + t] = red[wa][rr][0] + red[wa + 1][rr][0];
    dst[r0 + t] = red[wa][rr][1] + red[wa + 1][rr][1];
  }
}

// ---------- GAT aggregate, TWO nodes per call (one per 128-thr half) ----------
// Softmax per half (shfl + tiny LDS combine), then float4 k-slot gather:
// 4 slots x 32 cols per half -> dependent-load chain ~c/8 instead of c/2.
__device__ __forceinline__ void agg_pair(
    int i0, int s, int t, const float* __restrict__ Wh, const float* __restrict__ src,
    const float* __restrict__ dst, const int* __restrict__ idxbuf,
    const int* __restrict__ counts, float* tile, int (*jn)[128], float (*w)[128],
    float (*redm)[2], float (*reds)[2], float (*accs)[4][128]) {
  int half = t >> 7;        // which node of the pair
  int u = t & 127;          // lane within half
  int wv = (t >> 6) & 1;    // wave within half
  int i = i0 + s * 2 + half;
  int c = counts[i];
  float si = src[i];
  float e = -1e30f;
  if (u < c) {
    int j = idxbuf[(size_t)i * CAP + u];
    jn[half][u] = j;
    float xv = si + dst[j];
    e = xv > 0.f ? xv : LRELU_ALPHA * xv;
  }
  float m = e;
#pragma unroll
  for (int off = 32; off; off >>= 1) m = fmaxf(m, __shfl_xor(m, off));
  if ((t & 63) == 0) redm[half][wv] = m;
  __syncthreads();
  float M = fmaxf(redm[half][0], redm[half][1]);
  float ex = 0.f;
  if (u < c) {
    ex = expf(e - M);
    w[half][u] = ex;
  }
  float ss = ex;
#pragma unroll
  for (int off = 32; off; off >>= 1) ss += __shfl_xor(ss, off);
  if ((t & 63) == 0) reds[half][wv] = ss;
  __syncthreads();  // also publishes jn[half][]/w[half][]
  float inv = 1.f / (reds[half][0] + reds[half][1]);
  // ---- gather: slot = k residue mod 4, 32 threads x float4 cover a 512B row ----
  int slot = (t >> 5) & 3, col4 = t & 31;
  const float4* Wh4 = (const float4*)Wh;
  float ax = 0.f, ay = 0.f, az = 0.f, aw = 0.f;
  int k = slot;
  for (; k + 4 < c; k += 8) {  // 2 independent float4 loads per iteration
    float w0 = w[half][k], w1 = w[half][k + 4];
    float4 v0 = Wh4[(size_t)jn[half][k] * 32 + col4];
    float4 v1 = Wh4[(size_t)jn[half][k + 4] * 32 + col4];
    ax += w0 * v0.x + w1 * v1.x;
    ay += w0 * v0.y + w1 * v1.y;
    az += w0 * v0.z + w1 * v1.z;
    aw += w0 * v0.w + w1 * v1.w;
  }
  if (k < c) {
    float w0 = w[half][k];
    float4 v0 = Wh4[(size_t)jn[half][k] * 32 + col4];
    ax += w0 * v0.x; ay += w0 * v0.y; az += w0 * v0.z; aw += w0 * v0.w;
  }
  *(float4*)&accs[half][slot][col4 * 4] = make_float4(ax, ay, az, aw);
  __syncthreads();
  // combine 4 slot-partials per column (stride-1, conflict-free), ELU, write LDS tile
  float r = accs[half][0][u] + accs[half][1][u] + accs[half][2][u] + accs[half][3][u];
  r *= inv;
  tile[(s * 2 + half) * 128 + u] = r > 0.f ? r : expf(r) - 1.f;
  __syncthreads();  // protect jn/w/redm/reds/accs for next pair
}

// ======= kernel A: adj scan (blocks 0..8191) || gemm1+srcdst1 (..9215) || transpose (..9279) ==
__global__ __launch_bounds__(256) void kA(
    const float* __restrict__ adj, int* __restrict__ idxbuf, int* __restrict__ counts,
    const float* __restrict__ x, const float* __restrict__ W1, const float* __restrict__ a1,
    float* __restrict__ Wh1, float* __restrict__ src1, float* __restrict__ dst1,
    const float* __restrict__ Wi, const float* __restrict__ Whm, float* __restrict__ WiT,
    float* __restrict__ WhT) {
  __shared__ float As[8 * 256];
  __shared__ float red[4][4][2];
  __shared__ int jn[CAP];
  __shared__ int cnt;
  int t = threadIdx.x, b = blockIdx.x;
  if (b < N_NODES) {
    // ---- scan one adj row: 32 KB nontemporal stream, compact into LDS, write list ----
    if (t == 0) cnt = 0;
    __syncthreads();
    const v4f* row = (const v4f*)(adj + (size_t)b * N_NODES);
    v4f v[8];
#pragma unroll
    for (int u = 0; u < 8; u++) v[u] = __builtin_nontemporal_load(row + t + 256 * u);
#pragma unroll
    for (int u = 0; u < 8; u++) {
      int n = (v[u].x > 0.f) + (v[u].y > 0.f) + (v[u].z > 0.f) + (v[u].w > 0.f);
      if (n) {  // ~1.6% of threads
        int p = atomicAdd(&cnt, n);
        int j0 = (t + 256 * u) * 4;
        if (v[u].x > 0.f) { if (p < CAP) jn[p] = j0;     p++; }
        if (v[u].y > 0.f) { if (p < CAP) jn[p] = j0 + 1; p++; }
        if (v[u].z > 0.f) { if (p < CAP) jn[p] = j0 + 2; p++; }
        if (v[u].w > 0.f) { if (p < CAP) jn[p] = j0 + 3; p++; }
      }
    }
    __syncthreads();
    int c = cnt > CAP ? CAP : cnt;
    if (t < c) idxbuf[(size_t)b * CAP + t] = jn[t];
    if (t == 0) counts[b] = c;
  } else if (b < N_NODES + 1024) {
    int tile = b - N_NODES;
    const float4* Ab4 = (const float4*)(x + (size_t)tile * 8 * 256);
    float4* As4 = (float4*)As;
#pragma unroll
    for (int l = t; l < 8 * 256 / 4; l += 256) As4[l] = Ab4[l];
    __syncthreads();
    gemm_from_lds<256>(tile * 8, t, As, W1, a1, Wh1, src1, dst1, red);
  } else {
    for (int n = (b - N_NODES - 1024) * 256 + t; n < 384 * 128; n += 64 * 256) {
      int r = n >> 7, c = n & 127;
      WiT[c * 384 + r] = Wi[n];
      WhT[c * 384 + r] = Whm[n];
    }
  }
}

// ======= kernel B: agg1 for 8 nodes (4 pair-steps) -> LDS tile -> gemm2+srcdst2 ======
__global__ __launch_bounds__(256) void kB(
    const float* __restrict__ Wh1, const float* __restrict__ src1,
    const float* __restrict__ dst1, const int* __restrict__ idxbuf,
    const int* __restrict__ counts, const float* __restrict__ W2, const float* __restrict__ a2,
    float* __restrict__ Wh2, float* __restrict__ src2, float* __restrict__ dst2) {
  __shared__ float tile[8 * 128];
  __shared__ float red[4][4][2];
  __shared__ int jn[2][128];
  __shared__ float w[2][128];
  __shared__ float redm[2][2];
  __shared__ float reds[2][2];
  __shared__ float accs[2][4][128];
  int t = threadIdx.x, b = blockIdx.x;
  int i0 = b * 8;
#pragma unroll 1
  for (int s = 0; s < 4; s++)
    agg_pair(i0, s, t, Wh1, src1, dst1, idxbuf, counts, tile, jn, w, redm, reds, accs);
  // tile = x1 rows i0..i0+7 (ELU applied)
  gemm_from_lds<128>(i0, t, tile, W2, a2, Wh2, src2, dst2, red);
}

// ======= kernel C: agg2 for 8 nodes -> LDS tile -> GRU (h_spat never hits global) ======
__global__ __launch_bounds__(256) void kC(
    const float* __restrict__ Wh2, const float* __restrict__ src2,
    const float* __restrict__ dst2, const int* __restrict__ idxbuf,
    const int* __restrict__ counts, const float* __restrict__ hprev,
    const float* __restrict__ WiT, const float* __restrict__ WhT,
    const float* __restrict__ b_ih, const float* __restrict__ b_hh, float* __restrict__ outp) {
  __shared__ float tile[8 * 128];  // h_spat rows (GRU x-input)
  __shared__ float hs[8 * 128];    // hprev rows
  __shared__ int jn[2][128];
  __shared__ float w[2][128];
  __shared__ float redm[2][2];
  __shared__ float reds[2][2];
  __shared__ float accs[2][4][128];
  int t = threadIdx.x, b = blockIdx.x;
  int i0 = b * 8;
  // stage hprev early (ordered by agg barriers before use)
  ((float4*)hs)[t] = ((const float4*)(hprev + (size_t)i0 * 128))[t];
#pragma unroll 1
  for (int s = 0; s < 4; s++)
    agg_pair(i0, s, t, Wh2, src2, dst2, idxbuf, counts, tile, jn, w, redm, reds, accs);
  // ---- GRU on the tile ----
  int c = t & 127, half = t >> 7;
  const float* xsl = tile + half * 4 * 128;
  const float* hsl = hs + half * 4 * 128;
  float rg[4], zg[4];
  {
    float ai[4] = {0.f}, ah[4] = {0.f};
#pragma unroll 4
    for (int k = 0; k < 128; k++) {
      float wi = WiT[k * 384 + c], wh = WhT[k * 384 + c];
#pragma unroll
      for (int r = 0; r < 4; r++) { ai[r] += xsl[r * 128 + k] * wi; ah[r] += hsl[r * 128 + k] * wh; }
    }
    float bi = b_ih[c], bh = b_hh[c];
#pragma unroll
    for (int r = 0; r < 4; r++) rg[r] = 1.f / (1.f + expf(-(ai[r] + bi + ah[r] + bh)));
  }
  {
    float ai[4] = {0.f}, ah[4] = {0.f};
#pragma unroll 4
    for (int k = 0; k < 128; k++) {
      float wi = WiT[k * 384 + 128 + c], wh = WhT[k * 384 + 128 + c];
#pragma unroll
      for (int r = 0; r < 4; r++) { ai[r] += xsl[r * 128 + k] * wi; ah[r] += hsl[r * 128 + k] * wh; }
    }
    float bi = b_ih[128 + c], bh = b_hh[128 + c];
#pragma unroll
    for (int r = 0; r < 4; r++) zg[r] = 1.f / (1.f + expf(-(ai[r] + bi + ah[r] + bh)));
  }
  {
    float ai[4] = {0.f}, ah[4] = {0.f};
#pragma unroll 4
    for (int k = 0; k < 128; k++) {
      float wi = WiT[k * 384 + 256 + c], wh = WhT[k * 384 + 256 + c];
#pragma unroll
      for (int r = 0; r < 4; r++) { ai[r] += xsl[r * 128 + k] * wi; ah[r] += hsl[r * 128 + k] * wh; }
    }
    float bi = b_ih[256 + c], bh = b_hh[256 + c];
#pragma unroll
    for (int r = 0; r < 4; r++) {
      float n = tanhf(ai[r] + bi + rg[r] * (ah[r] + bh));
      outp[(size_t)(i0 + half * 4 + r) * 128 + c] =
          (1.f - zg[r]) * n + zg[r] * hsl[r * 128 + c];
    }
  }
}

extern "C" void kernel_launch(void* const* d_in, const int* in_sizes, int n_in,
                              void* d_out, int out_size, void* d_ws, size_t ws_size,
                              hipStream_t stream) {
  const float* x     = (const float*)d_in[0];
  const float* adj   = (const float*)d_in[1];
  const float* hprev = (const float*)d_in[2];
  const float* W1    = (const float*)d_in[3];
  const float* a1    = (const float*)d_in[4];
  const float* W2    = (const float*)d_in[5];
  const float* a2    = (const float*)d_in[6];
  const float* Wi    = (const float*)d_in[7];
  const float* Whm   = (const float*)d_in[8];
  const float* b_ih  = (const float*)d_in[9];
  const float* b_hh  = (const float*)d_in[10];
  float* outp = (float*)d_out;

  char* p = (char*)d_ws;
  float* Wh1    = (float*)p; p += (size_t)N_NODES * 128 * 4;
  float* Wh2    = (float*)p; p += (size_t)N_NODES * 128 * 4;
  float* src1   = (float*)p; p += (size_t)N_NODES * 4;
  float* dst1   = (float*)p; p += (size_t)N_NODES * 4;
  float* src2   = (float*)p; p += (size_t)N_NODES * 4;
  float* dst2   = (float*)p; p += (size_t)N_NODES * 4;
  float* WiT    = (float*)p; p += (size_t)384 * 128 * 4;
  float* WhT    = (float*)p; p += (size_t)384 * 128 * 4;
  int*   counts = (int*)p;   p += (size_t)N_NODES * 4;
  int*   idxbuf = (int*)p;   p += (size_t)N_NODES * CAP * 4;

  // A: adj scan (8192 blocks, full parallelism) || gemm1+srcdst1 || GRU-weight transpose
  kA<<<N_NODES + 1024 + 64, 256, 0, stream>>>(adj, idxbuf, counts, x, W1, a1, Wh1, src1, dst1,
                                              Wi, Whm, WiT, WhT);
  // B: agg1 (paired, float4 k-slot gather) -> LDS x1 tile -> gemm2+srcdst2
  kB<<<N_NODES / 8, 256, 0, stream>>>(Wh1, src1, dst1, idxbuf, counts, W2, a2, Wh2, src2, dst2);
  // C: agg2 -> LDS h_spat tile -> GRU
  kC<<<N_NODES / 8, 256, 0, stream>>>(Wh2, src2, dst2, idxbuf, counts, hprev, WiT, WhT, b_ih,
                                      b_hh, outp);
}